// Round 2
// baseline (292.822 us; speedup 1.0000x reference)
//
#include <hip/hip_runtime.h>

#define MAXB 1024
#define DIAGF 0x40000000

// Per-graph start offsets (reference: counts -> cumsum). One block.
__global__ void offsets_k(const int* __restrict__ bv, int N,
                          const int* __restrict__ eb, int E,
                          const int* __restrict__ nG,
                          int* __restrict__ node_off, int* __restrict__ e_off) {
    __shared__ int c1[MAXB];
    __shared__ int c2[MAXB];
    int B = nG[0];
    if (B > MAXB) B = MAXB;
    for (int i = threadIdx.x; i < B; i += blockDim.x) { c1[i] = 0; c2[i] = 0; }
    __syncthreads();
    for (int i = threadIdx.x; i < N; i += blockDim.x) atomicAdd(&c1[bv[i]], 1);
    for (int i = threadIdx.x; i < E; i += blockDim.x) atomicAdd(&c2[eb[i]], 1);
    __syncthreads();
    if (threadIdx.x == 0) {
        int a = 0, b = 0;
        for (int g = 0; g < B; ++g) {
            node_off[g] = a; a += c1[g];
            e_off[g]    = b; b += c2[g];
        }
    }
}

// Cell-type map: -1 = disconnected, -2 = diag(non-edge), else id | DIAGF?
__global__ void map_init_k(int* __restrict__ map, int C) {
    int stride = gridDim.x * blockDim.x;
    for (int i = blockIdx.x * blockDim.x + threadIdx.x; i < C; i += stride)
        map[i] = -1;
}

__global__ void map_diag_k(const int* __restrict__ nG, int N, int E,
                           int* __restrict__ map) {
    int t = blockIdx.x * blockDim.x + threadIdx.x;
    if (t >= N + E) return;
    int B = nG[0];
    int n = N / B, Eg = E / B;
    int C1 = N * n;  // B*n*n
    int cell;
    if (t < N) {
        int g = t / n, l = t - g * n;
        cell = (g * n + l) * n + l;
    } else {
        int u = t - N;
        int g = u / Eg, l = u - g * Eg;
        cell = C1 + (g * Eg + l) * Eg + l;
    }
    map[cell] = -2;
}

__global__ void map_scatter_k(const int* __restrict__ ei,
                              const int* __restrict__ bv,
                              const int* __restrict__ node_off,
                              const int* __restrict__ e2e_ei,
                              const int* __restrict__ eb,
                              const int* __restrict__ e_off,
                              const int* __restrict__ nidx,
                              const int* __restrict__ nG,
                              int N, int E, int E2, int* __restrict__ map) {
    int t = blockIdx.x * blockDim.x + threadIdx.x;
    if (t >= E + E2) return;
    int B = nG[0];
    int n = N / B, Eg = E / B;
    int C1 = N * n;
    if (t < E) {
        int e = t;
        int s = ei[e], d = ei[E + e];
        int g = bv[s];
        int li = s - node_off[g], lj = d - node_off[g];
        map[(g * n + li) * n + lj] = e | (li == lj ? DIAGF : 0);
    } else {
        int f = t - E;
        int es = e2e_ei[f], ed = e2e_ei[E2 + f];
        int g = eb[es];
        int li = es - e_off[g], lj = ed - e_off[g];
        map[C1 + (g * Eg + li) * Eg + lj] = nidx[f] | (li == lj ? DIAGF : 0);
    }
}

__global__ void x2_copy_k(const float4* __restrict__ x, float4* __restrict__ x2, int n4) {
    int t = blockIdx.x * blockDim.x + threadIdx.x;
    if (t < n4) x2[t] = x[t];
}

// x2 += segment_sum(edge_attr, dst)
__global__ void x2_add_k(const float* __restrict__ edge_attr,
                         const int* __restrict__ edge_index,
                         int E, int emb, float* __restrict__ x2) {
    int t = blockIdx.x * blockDim.x + threadIdx.x;
    if (t >= E * emb) return;
    int e = t / emb;
    int c = t - e * emb;
    int dst = edge_index[E + e];  // row 1 of (2,E)
    atomicAdd(&x2[dst * emb + c], edge_attr[t]);
}

// Single-pass writer: one wave per output cell, lane = float4 column.
// No integer division, every output float4 written exactly once.
__global__ __launch_bounds__(256) void main_k(
    const int* __restrict__ map,
    const float4* __restrict__ edge_attr,
    const float4* __restrict__ x,
    const float4* __restrict__ x2,
    const int* __restrict__ ei,
    const float4* __restrict__ encW,
    const float4* __restrict__ e2eW,
    const int* __restrict__ nG,
    int N, int E, int emb4, int C,
    float4* __restrict__ out) {
    int B = nG[0];
    int n = N / B;
    int C1 = N * n;  // B*n*n cells in edge_dense region
    int lane = threadIdx.x & 63;
    int wave = (blockIdx.x * blockDim.x + threadIdx.x) >> 6;
    int nw   = (gridDim.x * blockDim.x) >> 6;
    for (int cell = wave; cell < C; cell += nw) {
        int m = map[cell];
        const float4* W = (cell < C1) ? encW : e2eW;
        for (int c4 = lane; c4 < emb4; c4 += 64) {
            float4 v;
            if (m == -1) {                       // disconnected -> W[2]
                v = W[2 * emb4 + c4];
            } else if (m == -2) {                // diag non-edge -> W[1]
                v = W[emb4 + c4];
            } else {
                int id = m & 0x3FFFFFFF;
                if (cell < C1) {                 // edge cell: ea + x[src] + x[dst]
                    int s = ei[id], d = ei[E + id];
                    float4 a  = edge_attr[(long)id * emb4 + c4];
                    float4 xs = x[(long)s * emb4 + c4];
                    float4 xd = x[(long)d * emb4 + c4];
                    v.x = a.x + xs.x + xd.x;
                    v.y = a.y + xs.y + xd.y;
                    v.z = a.z + xs.z + xd.z;
                    v.w = a.w + xs.w + xd.w;
                } else {                         // e2e cell: x2[node]
                    v = x2[(long)id * emb4 + c4];
                }
                if (m & DIAGF) {                 // edge on diag: adj==3 -> +W[2]
                    float4 w2 = W[2 * emb4 + c4];
                    v.x += w2.x; v.y += w2.y; v.z += w2.z; v.w += w2.w;
                }
            }
            out[(long)cell * emb4 + c4] = v;
        }
    }
}

extern "C" void kernel_launch(void* const* d_in, const int* in_sizes, int n_in,
                              void* d_out, int out_size, void* d_ws, size_t ws_size,
                              hipStream_t stream) {
    const float* x          = (const float*)d_in[0];
    const float* edge_attr  = (const float*)d_in[1];
    const float* enc_W      = (const float*)d_in[2];
    const float* e2e_W      = (const float*)d_in[3];
    const int* edge_index   = (const int*)d_in[4];
    const int* batch_vec    = (const int*)d_in[5];
    const int* e2e_ei       = (const int*)d_in[6];
    const int* e_batch      = (const int*)d_in[7];
    const int* e2e_nidx     = (const int*)d_in[8];
    const int* nG           = (const int*)d_in[9];

    int emb  = in_sizes[2] / 3;        // enc_W is (3, emb)
    int emb4 = emb / 4;
    int N    = in_sizes[0] / emb;      // x is (N, emb)
    int E    = in_sizes[1] / emb;      // edge_attr is (E, emb)
    int E2   = in_sizes[8];            // e2e_node_index is (E2,)
    int C    = out_size / emb;         // total output cells (out_size is in floats)

    char* ws      = (char*)d_ws;
    int* node_off = (int*)ws;                              // up to MAXB ints
    int* e_off    = (int*)(ws + 4096);                     // up to MAXB ints
    float* x2     = (float*)(ws + 8192);                   // N*emb floats
    int* map      = (int*)(ws + 8192 + (size_t)N * emb * 4); // C ints

    offsets_k<<<1, 256, 0, stream>>>(batch_vec, N, e_batch, E, nG, node_off, e_off);

    map_init_k<<<1024, 256, 0, stream>>>(map, C);

    map_diag_k<<<(N + E + 255) / 256, 256, 0, stream>>>(nG, N, E, map);

    map_scatter_k<<<(E + E2 + 255) / 256, 256, 0, stream>>>(
        edge_index, batch_vec, node_off, e2e_ei, e_batch, e_off,
        e2e_nidx, nG, N, E, E2, map);

    int n4x = (N * emb) / 4;
    x2_copy_k<<<(n4x + 255) / 256, 256, 0, stream>>>((const float4*)x, (float4*)x2, n4x);

    int tadd = E * emb;
    x2_add_k<<<(tadd + 255) / 256, 256, 0, stream>>>(edge_attr, edge_index, E, emb, x2);

    main_k<<<8192, 256, 0, stream>>>(
        map, (const float4*)edge_attr, (const float4*)x, (const float4*)x2,
        edge_index, (const float4*)enc_W, (const float4*)e2e_W,
        nG, N, E, emb4, C, (float4*)d_out);
}

// Round 4
// 292.385 us; speedup vs baseline: 1.0015x; 1.0015x over previous
//
#include <hip/hip_runtime.h>

#define MAXB 1024
#define DIAGF 0x40000000

typedef float nat_f4 __attribute__((ext_vector_type(4)));

// Phase 1 (one dispatch):
//  - block 0: per-graph start offsets (counts -> cumsum)
//  - all blocks grid-stride: map[] = -1, x2 = x (copy)
__global__ void prep1_k(const int* __restrict__ bv, int N,
                        const int* __restrict__ eb, int E,
                        const int* __restrict__ nG,
                        int* __restrict__ node_off, int* __restrict__ e_off,
                        int* __restrict__ map, int C,
                        const float4* __restrict__ x, float4* __restrict__ x2,
                        int n4) {
    if (blockIdx.x == 0) {
        __shared__ int c1[MAXB];
        __shared__ int c2[MAXB];
        int B = nG[0];
        if (B > MAXB) B = MAXB;
        for (int i = threadIdx.x; i < B; i += blockDim.x) { c1[i] = 0; c2[i] = 0; }
        __syncthreads();
        for (int i = threadIdx.x; i < N; i += blockDim.x) atomicAdd(&c1[bv[i]], 1);
        for (int i = threadIdx.x; i < E; i += blockDim.x) atomicAdd(&c2[eb[i]], 1);
        __syncthreads();
        if (threadIdx.x == 0) {
            int a = 0, b = 0;
            for (int g = 0; g < B; ++g) {
                node_off[g] = a; a += c1[g];
                e_off[g]    = b; b += c2[g];
            }
        }
    }
    int stride = gridDim.x * blockDim.x;
    int t0 = blockIdx.x * blockDim.x + threadIdx.x;
    for (int i = t0; i < C; i += stride) map[i] = -1;
    for (int i = t0; i < n4; i += stride) x2[i] = x[i];
}

// Phase 2 (one dispatch): diag marks (CAS), edge/e2e scatter (store), x2 += seg-sum.
// CAS(-1 -> -2) for diag vs plain store for scatter commute: either order gives
// the correct final value (edge ids are >= 0, never -1).
__global__ void prep2_k(const int* __restrict__ ei,
                        const int* __restrict__ bv,
                        const int* __restrict__ node_off,
                        const int* __restrict__ e2e_ei,
                        const int* __restrict__ eb,
                        const int* __restrict__ e_off,
                        const int* __restrict__ nidx,
                        const int* __restrict__ nG,
                        const float* __restrict__ edge_attr,
                        float* __restrict__ x2,
                        int N, int E, int E2, int emb,
                        int* __restrict__ map) {
    int B = nG[0];
    int n = N / B, Eg = E / B;
    int C1 = N * n;
    int stride = gridDim.x * blockDim.x;
    int t0 = blockIdx.x * blockDim.x + threadIdx.x;

    // diag cells
    for (int t = t0; t < N + E; t += stride) {
        int cell;
        if (t < N) {
            int g = t / n, l = t - g * n;
            cell = (g * n + l) * n + l;
        } else {
            int u = t - N;
            int g = u / Eg, l = u - g * Eg;
            cell = C1 + (g * Eg + l) * Eg + l;
        }
        atomicCAS(&map[cell], -1, -2);
    }

    // edge + e2e scatter
    for (int t = t0; t < E + E2; t += stride) {
        if (t < E) {
            int e = t;
            int s = ei[e], d = ei[E + e];
            int g = bv[s];
            int li = s - node_off[g], lj = d - node_off[g];
            map[(g * n + li) * n + lj] = e | (li == lj ? DIAGF : 0);
        } else {
            int f = t - E;
            int es = e2e_ei[f], ed = e2e_ei[E2 + f];
            int g = eb[es];
            int li = es - e_off[g], lj = ed - e_off[g];
            map[C1 + (g * Eg + li) * Eg + lj] = nidx[f] | (li == lj ? DIAGF : 0);
        }
    }

    // x2 += segment_sum(edge_attr, dst)
    int T3 = E * emb;
    for (int t = t0; t < T3; t += stride) {
        int e = t / emb;
        int c = t - e * emb;
        int dst = ei[E + e];  // row 1 of (2,E)
        atomicAdd(&x2[dst * emb + c], edge_attr[t]);
    }
}

// Single-pass writer: one wave per output cell, lane = float4 column.
// No integer division; every output float4 written exactly once (non-temporal).
__global__ __launch_bounds__(256) void main_k(
    const int* __restrict__ map,
    const float4* __restrict__ edge_attr,
    const float4* __restrict__ x,
    const float4* __restrict__ x2,
    const int* __restrict__ ei,
    const float4* __restrict__ encW,
    const float4* __restrict__ e2eW,
    const int* __restrict__ nG,
    int N, int E, int emb4, int C,
    float4* __restrict__ out) {
    int B = nG[0];
    int n = N / B;
    int C1 = N * n;  // B*n*n cells in edge_dense region
    int lane = threadIdx.x & 63;
    int wave = (blockIdx.x * blockDim.x + threadIdx.x) >> 6;
    int nw   = (gridDim.x * blockDim.x) >> 6;
    for (int cell = wave; cell < C; cell += nw) {
        int m = map[cell];
        const float4* W = (cell < C1) ? encW : e2eW;
        for (int c4 = lane; c4 < emb4; c4 += 64) {
            float4 v;
            if (m == -1) {                       // disconnected -> W[2]
                v = W[2 * emb4 + c4];
            } else if (m == -2) {                // diag non-edge -> W[1]
                v = W[emb4 + c4];
            } else {
                int id = m & 0x3FFFFFFF;
                if (cell < C1) {                 // edge cell: ea + x[src] + x[dst]
                    int s = ei[id], d = ei[E + id];
                    float4 a  = edge_attr[(long)id * emb4 + c4];
                    float4 xs = x[(long)s * emb4 + c4];
                    float4 xd = x[(long)d * emb4 + c4];
                    v.x = a.x + xs.x + xd.x;
                    v.y = a.y + xs.y + xd.y;
                    v.z = a.z + xs.z + xd.z;
                    v.w = a.w + xs.w + xd.w;
                } else {                         // e2e cell: x2[node]
                    v = x2[(long)id * emb4 + c4];
                }
                if (m & DIAGF) {                 // edge on diag: adj==3 -> +W[2]
                    float4 w2 = W[2 * emb4 + c4];
                    v.x += w2.x; v.y += w2.y; v.z += w2.z; v.w += w2.w;
                }
            }
            nat_f4 nv;
            nv.x = v.x; nv.y = v.y; nv.z = v.z; nv.w = v.w;
            __builtin_nontemporal_store(nv, (nat_f4*)&out[(long)cell * emb4 + c4]);
        }
    }
}

extern "C" void kernel_launch(void* const* d_in, const int* in_sizes, int n_in,
                              void* d_out, int out_size, void* d_ws, size_t ws_size,
                              hipStream_t stream) {
    const float* x          = (const float*)d_in[0];
    const float* edge_attr  = (const float*)d_in[1];
    const float* enc_W      = (const float*)d_in[2];
    const float* e2e_W      = (const float*)d_in[3];
    const int* edge_index   = (const int*)d_in[4];
    const int* batch_vec    = (const int*)d_in[5];
    const int* e2e_ei       = (const int*)d_in[6];
    const int* e_batch      = (const int*)d_in[7];
    const int* e2e_nidx     = (const int*)d_in[8];
    const int* nG           = (const int*)d_in[9];

    int emb  = in_sizes[2] / 3;        // enc_W is (3, emb)
    int emb4 = emb / 4;
    int N    = in_sizes[0] / emb;      // x is (N, emb)
    int E    = in_sizes[1] / emb;      // edge_attr is (E, emb)
    int E2   = in_sizes[8];            // e2e_node_index is (E2,)
    int C    = out_size / emb;         // total output cells (out_size is in floats)

    char* ws      = (char*)d_ws;
    int* node_off = (int*)ws;                              // up to MAXB ints
    int* e_off    = (int*)(ws + 4096);                     // up to MAXB ints
    float* x2     = (float*)(ws + 8192);                   // N*emb floats
    int* map      = (int*)(ws + 8192 + (size_t)N * emb * 4); // C ints

    int n4x = (N * emb) / 4;
    prep1_k<<<1024, 256, 0, stream>>>(batch_vec, N, e_batch, E, nG,
                                      node_off, e_off, map, C,
                                      (const float4*)x, (float4*)x2, n4x);

    prep2_k<<<1024, 256, 0, stream>>>(edge_index, batch_vec, node_off,
                                      e2e_ei, e_batch, e_off, e2e_nidx, nG,
                                      edge_attr, x2, N, E, E2, emb, map);

    main_k<<<8192, 256, 0, stream>>>(
        map, (const float4*)edge_attr, (const float4*)x, (const float4*)x2,
        edge_index, (const float4*)enc_W, (const float4*)e2e_W,
        nG, N, E, emb4, C, (float4*)d_out);
}